// Round 1
// baseline (567.709 us; speedup 1.0000x reference)
//
#include <hip/hip_runtime.h>
#include <math.h>

#define D 128          // feature dim (d_in = d_h = 128)
#define BM 64
#define BN 64
#define BK 16

// ---------------- CSR build ----------------

__global__ void init_kernel(int* cnt, int* curs, int n) {
    int i = blockIdx.x * blockDim.x + threadIdx.x;
    if (i < n) { cnt[i] = 0; curs[i] = 0; }
}

__global__ void count_kernel(const int* col, int* cnt, int E) {
    int e = blockIdx.x * blockDim.x + threadIdx.x;
    if (e < E) atomicAdd(&cnt[col[e]], 1);
}

// single-block exclusive scan over n counts -> offsets[0..n]
__global__ void scan_kernel(const int* cnt, int* offs, int n) {
    __shared__ int part[1024];
    int t = threadIdx.x;
    int CH = (n + 1023) / 1024;
    int start = t * CH;
    int end = start + CH; if (end > n) end = n;
    int s = 0;
    for (int i = start; i < end; i++) s += cnt[i];
    part[t] = s;
    __syncthreads();
    for (int off = 1; off < 1024; off <<= 1) {
        int v = (t >= off) ? part[t - off] : 0;
        __syncthreads();
        part[t] += v;
        __syncthreads();
    }
    int base = (t == 0) ? 0 : part[t - 1];
    int run = base;
    for (int i = start; i < end; i++) { offs[i] = run; run += cnt[i]; }
    if (t == 1023) offs[n] = part[1023];
}

__global__ void fill_kernel(const int* row, const int* col, const int* offs,
                            int* curs, int* adj, int E) {
    int e = blockIdx.x * blockDim.x + threadIdx.x;
    if (e < E) {
        int c = col[e];
        int p = atomicAdd(&curs[c], 1);
        adj[offs[c] + p] = row[e];
    }
}

__global__ void dinv_kernel(const int* cnt, float* dinv, int n) {
    int i = blockIdx.x * blockDim.x + threadIdx.x;
    if (i < n) dinv[i] = rsqrtf((float)cnt[i] + 1.0f);
}

// ---------------- GEMM: C[M x 128] = A[M x 128] @ W[128 x 128] ----------------

__global__ __launch_bounds__(256) void gemm128_kernel(const float* __restrict__ A,
                                                      const float* __restrict__ W,
                                                      float* __restrict__ C, int M) {
    __shared__ float As[BK][BM + 4];
    __shared__ float Bs[BK][BN + 4];
    int bm = blockIdx.y, bn = blockIdx.x;
    int t = threadIdx.x;
    int tc = t & 15, tr = t >> 4;

    int arow = t >> 2;   // 0..63
    int akq  = t & 3;    // k-quad
    int brow = t >> 4;   // 0..15 (k within tile)
    int bcq  = t & 15;   // col quad
    int grow = bm * BM + arow;

    float acc[4][4] = {};

    for (int k0 = 0; k0 < D; k0 += BK) {
        float4 av;
        if (grow < M)
            av = *(const float4*)(A + (size_t)grow * D + k0 + akq * 4);
        else
            av = make_float4(0.f, 0.f, 0.f, 0.f);
        As[akq * 4 + 0][arow] = av.x;
        As[akq * 4 + 1][arow] = av.y;
        As[akq * 4 + 2][arow] = av.z;
        As[akq * 4 + 3][arow] = av.w;

        float4 bv = *(const float4*)(W + (size_t)(k0 + brow) * D + bn * BN + bcq * 4);
        *(float4*)&Bs[brow][bcq * 4] = bv;
        __syncthreads();

#pragma unroll
        for (int kk = 0; kk < BK; kk++) {
            float4 a = *(const float4*)&As[kk][tr * 4];
            float4 b = *(const float4*)&Bs[kk][tc * 4];
            acc[0][0] += a.x * b.x; acc[0][1] += a.x * b.y; acc[0][2] += a.x * b.z; acc[0][3] += a.x * b.w;
            acc[1][0] += a.y * b.x; acc[1][1] += a.y * b.y; acc[1][2] += a.y * b.z; acc[1][3] += a.y * b.w;
            acc[2][0] += a.z * b.x; acc[2][1] += a.z * b.y; acc[2][2] += a.z * b.z; acc[2][3] += a.z * b.w;
            acc[3][0] += a.w * b.x; acc[3][1] += a.w * b.y; acc[3][2] += a.w * b.z; acc[3][3] += a.w * b.w;
        }
        __syncthreads();
    }

    int crow = bm * BM + tr * 4;
    int ccol = bn * BN + tc * 4;
#pragma unroll
    for (int r = 0; r < 4; r++) {
        if (crow + r < M) {
            float4 o = make_float4(acc[r][0], acc[r][1], acc[r][2], acc[r][3]);
            *(float4*)(C + (size_t)(crow + r) * D + ccol) = o;
        }
    }
}

// ---------------- aggregation: one wave per node ----------------
// hout[i,:] = relu(b + dinv[i]*(dinv[i]*xw[i,:] + sum_{r in in(i)} dinv[r]*xw[r,:]))

__global__ __launch_bounds__(256) void agg_kernel(const float* __restrict__ xw,
                                                  const int* __restrict__ adj,
                                                  const int* __restrict__ offs,
                                                  const float* __restrict__ dinv,
                                                  const float* __restrict__ bias,
                                                  float* __restrict__ hout, int n) {
    int wave = (int)((blockIdx.x * (size_t)blockDim.x + threadIdx.x) >> 6);
    int lane = threadIdx.x & 63;
    if (wave >= n) return;
    int i = wave;
    float di = dinv[i];
    float2 self = ((const float2*)(xw + (size_t)i * D))[lane];
    float acc0 = di * self.x;
    float acc1 = di * self.y;
    int s = offs[i], e = offs[i + 1];
    for (int j = s; j < e; j++) {
        int r = adj[j];
        float dr = dinv[r];
        float2 v = ((const float2*)(xw + (size_t)r * D))[lane];
        acc0 = fmaf(dr, v.x, acc0);
        acc1 = fmaf(dr, v.y, acc1);
    }
    float2 bv = ((const float2*)bias)[lane];
    float o0 = fmaxf(fmaf(di, acc0, bv.x), 0.f);
    float o1 = fmaxf(fmaf(di, acc1, bv.y), 0.f);
    ((float2*)(hout + (size_t)i * D))[lane] = make_float2(o0, o1);
}

// ---------------- edge classifier: one wave per edge ----------------

__global__ __launch_bounds__(256) void edge_kernel(const float* __restrict__ h,
                                                   const int* __restrict__ row,
                                                   const int* __restrict__ col,
                                                   const float* __restrict__ Wfc,
                                                   const float* __restrict__ bfc,
                                                   float* __restrict__ out, int E) {
    int wave = (int)((blockIdx.x * (size_t)blockDim.x + threadIdx.x) >> 6);
    int lane = threadIdx.x & 63;
    if (wave >= E) return;
    int r = row[wave], c = col[wave];
    const float* hr = h + (size_t)r * D;
    const float* hc = h + (size_t)c * D;
    float a0 = hr[lane], a1 = hr[lane + 64];
    float b0 = hc[lane], b1 = hc[lane + 64];
    const float4* W4 = (const float4*)Wfc;  // 256 rows x 4
    float sx = 0.f, sy = 0.f, sz = 0.f, sw = 0.f;
    float4 w;
    w = W4[lane];
    sx = fmaf(a0, w.x, sx); sy = fmaf(a0, w.y, sy); sz = fmaf(a0, w.z, sz); sw = fmaf(a0, w.w, sw);
    w = W4[lane + 64];
    sx = fmaf(a1, w.x, sx); sy = fmaf(a1, w.y, sy); sz = fmaf(a1, w.z, sz); sw = fmaf(a1, w.w, sw);
    w = W4[128 + lane];
    sx = fmaf(b0, w.x, sx); sy = fmaf(b0, w.y, sy); sz = fmaf(b0, w.z, sz); sw = fmaf(b0, w.w, sw);
    w = W4[192 + lane];
    sx = fmaf(b1, w.x, sx); sy = fmaf(b1, w.y, sy); sz = fmaf(b1, w.z, sz); sw = fmaf(b1, w.w, sw);

#pragma unroll
    for (int off = 32; off > 0; off >>= 1) {
        sx += __shfl_xor(sx, off, 64);
        sy += __shfl_xor(sy, off, 64);
        sz += __shfl_xor(sz, off, 64);
        sw += __shfl_xor(sw, off, 64);
    }
    if (lane == 0) {
        sx += bfc[0]; sy += bfc[1]; sz += bfc[2]; sw += bfc[3];
        float m = fmaxf(fmaxf(sx, sy), fmaxf(sz, sw));
        float e0 = expf(sx - m), e1 = expf(sy - m), e2 = expf(sz - m), e3 = expf(sw - m);
        float lse = m + logf(e0 + e1 + e2 + e3);
        float4 o = make_float4(sx - lse, sy - lse, sz - lse, sw - lse);
        *(float4*)(out + (size_t)wave * 4) = o;
    }
}

// ---------------- launch ----------------

extern "C" void kernel_launch(void* const* d_in, const int* in_sizes, int n_in,
                              void* d_out, int out_size, void* d_ws, size_t ws_size,
                              hipStream_t stream) {
    const float* x   = (const float*)d_in[0];
    const int*   ei  = (const int*)d_in[1];
    const float* W1  = (const float*)d_in[2];
    const float* b1  = (const float*)d_in[3];
    const float* W2  = (const float*)d_in[4];
    const float* b2  = (const float*)d_in[5];
    const float* Wfc = (const float*)d_in[6];
    const float* bfc = (const float*)d_in[7];
    float* out = (float*)d_out;

    int n = in_sizes[0] / D;        // 50000
    int E = in_sizes[1] / 2;        // 600000
    const int* row = ei;            // edge_index[0]
    const int* col = ei + E;        // edge_index[1]

    // workspace layout (floats/ints)
    float* bufA = (float*)d_ws;                 // n*D
    float* bufB = bufA + (size_t)n * D;         // n*D
    int*   cnt  = (int*)(bufB + (size_t)n * D); // n
    int*   offs = cnt + n;                      // n+1
    int*   curs = offs + (n + 1);               // n
    int*   adj  = curs + n;                     // E
    float* dinv = (float*)(adj + E);            // n

    int nb_n = (n + 255) / 256;
    int nb_e = (E + 255) / 256;

    // CSR build
    init_kernel<<<nb_n, 256, 0, stream>>>(cnt, curs, n);
    count_kernel<<<nb_e, 256, 0, stream>>>(col, cnt, E);
    scan_kernel<<<1, 1024, 0, stream>>>(cnt, offs, n);
    fill_kernel<<<nb_e, 256, 0, stream>>>(row, col, offs, curs, adj, E);
    dinv_kernel<<<nb_n, 256, 0, stream>>>(cnt, dinv, n);

    dim3 gg(D / BN, (n + BM - 1) / BM);

    // layer 1
    gemm128_kernel<<<gg, 256, 0, stream>>>(x, W1, bufA, n);
    agg_kernel<<<(n + 3) / 4, 256, 0, stream>>>(bufA, adj, offs, dinv, b1, bufB, n);
    // layer 2
    gemm128_kernel<<<gg, 256, 0, stream>>>(bufB, W2, bufA, n);
    agg_kernel<<<(n + 3) / 4, 256, 0, stream>>>(bufA, adj, offs, dinv, b2, bufB, n);
    // edge classifier
    edge_kernel<<<(E + 3) / 4, 256, 0, stream>>>(bufB, row, col, Wfc, bfc, out, E);
}

// Round 2
// 401.192 us; speedup vs baseline: 1.4151x; 1.4151x over previous
//
#include <hip/hip_runtime.h>
#include <math.h>

#define D 128          // feature dim (d_in = d_h = 128)
#define BM 64
#define BN 64
#define BK 16

// ---------------- CSR build ----------------

__global__ void init_kernel(int* cnt, int* curs, int n) {
    int i = blockIdx.x * blockDim.x + threadIdx.x;
    if (i < n) { cnt[i] = 0; curs[i] = 0; }
}

__global__ void count_kernel(const int* col, int* cnt, int E) {
    int e = blockIdx.x * blockDim.x + threadIdx.x;
    if (e < E) atomicAdd(&cnt[col[e]], 1);
}

// single-block exclusive scan over n counts -> offsets[0..n]
__global__ void scan_kernel(const int* cnt, int* offs, int n) {
    __shared__ int part[1024];
    int t = threadIdx.x;
    int CH = (n + 1023) / 1024;
    int start = t * CH;
    int end = start + CH; if (end > n) end = n;
    int s = 0;
    for (int i = start; i < end; i++) s += cnt[i];
    part[t] = s;
    __syncthreads();
    for (int off = 1; off < 1024; off <<= 1) {
        int v = (t >= off) ? part[t - off] : 0;
        __syncthreads();
        part[t] += v;
        __syncthreads();
    }
    int base = (t == 0) ? 0 : part[t - 1];
    int run = base;
    for (int i = start; i < end; i++) { offs[i] = run; run += cnt[i]; }
    if (t == 1023) offs[n] = part[1023];
}

__global__ void fill_kernel(const int* row, const int* col, const int* offs,
                            int* curs, int* adj, int E) {
    int e = blockIdx.x * blockDim.x + threadIdx.x;
    if (e < E) {
        int c = col[e];
        int p = atomicAdd(&curs[c], 1);
        adj[offs[c] + p] = row[e];
    }
}

__global__ void dinv_kernel(const int* cnt, float* dinv, int n) {
    int i = blockIdx.x * blockDim.x + threadIdx.x;
    if (i < n) dinv[i] = rsqrtf((float)cnt[i] + 1.0f);
}

// ---------------- GEMM: C[M x 128] = A[M x 128] @ W[128 x 128] ----------------

__global__ __launch_bounds__(256) void gemm128_kernel(const float* __restrict__ A,
                                                      const float* __restrict__ W,
                                                      float* __restrict__ C, int M) {
    __shared__ float As[BK][BM + 4];
    __shared__ float Bs[BK][BN + 4];
    int bm = blockIdx.y, bn = blockIdx.x;
    int t = threadIdx.x;
    int tc = t & 15, tr = t >> 4;

    int arow = t >> 2;   // 0..63
    int akq  = t & 3;    // k-quad
    int brow = t >> 4;   // 0..15 (k within tile)
    int bcq  = t & 15;   // col quad
    int grow = bm * BM + arow;

    float acc[4][4] = {};

    for (int k0 = 0; k0 < D; k0 += BK) {
        float4 av;
        if (grow < M)
            av = *(const float4*)(A + (size_t)grow * D + k0 + akq * 4);
        else
            av = make_float4(0.f, 0.f, 0.f, 0.f);
        As[akq * 4 + 0][arow] = av.x;
        As[akq * 4 + 1][arow] = av.y;
        As[akq * 4 + 2][arow] = av.z;
        As[akq * 4 + 3][arow] = av.w;

        float4 bv = *(const float4*)(W + (size_t)(k0 + brow) * D + bn * BN + bcq * 4);
        *(float4*)&Bs[brow][bcq * 4] = bv;
        __syncthreads();

#pragma unroll
        for (int kk = 0; kk < BK; kk++) {
            float4 a = *(const float4*)&As[kk][tr * 4];
            float4 b = *(const float4*)&Bs[kk][tc * 4];
            acc[0][0] += a.x * b.x; acc[0][1] += a.x * b.y; acc[0][2] += a.x * b.z; acc[0][3] += a.x * b.w;
            acc[1][0] += a.y * b.x; acc[1][1] += a.y * b.y; acc[1][2] += a.y * b.z; acc[1][3] += a.y * b.w;
            acc[2][0] += a.z * b.x; acc[2][1] += a.z * b.y; acc[2][2] += a.z * b.z; acc[2][3] += a.z * b.w;
            acc[3][0] += a.w * b.x; acc[3][1] += a.w * b.y; acc[3][2] += a.w * b.z; acc[3][3] += a.w * b.w;
        }
        __syncthreads();
    }

    int crow = bm * BM + tr * 4;
    int ccol = bn * BN + tc * 4;
#pragma unroll
    for (int r = 0; r < 4; r++) {
        if (crow + r < M) {
            float4 o = make_float4(acc[r][0], acc[r][1], acc[r][2], acc[r][3]);
            *(float4*)(C + (size_t)(crow + r) * D + ccol) = o;
        }
    }
}

// ---------------- aggregation: one wave per node ----------------
// hout[i,:] = relu(b + dinv[i]*(dinv[i]*xw[i,:] + sum_{r in in(i)} dinv[r]*xw[r,:]))

__global__ __launch_bounds__(256) void agg_kernel(const float* __restrict__ xw,
                                                  const int* __restrict__ adj,
                                                  const int* __restrict__ offs,
                                                  const float* __restrict__ dinv,
                                                  const float* __restrict__ bias,
                                                  float* __restrict__ hout, int n) {
    int wave = (int)((blockIdx.x * (size_t)blockDim.x + threadIdx.x) >> 6);
    int lane = threadIdx.x & 63;
    if (wave >= n) return;
    int i = wave;
    float di = dinv[i];
    float2 self = ((const float2*)(xw + (size_t)i * D))[lane];
    float acc0 = di * self.x;
    float acc1 = di * self.y;
    int s = offs[i], e = offs[i + 1];
    int j = s;
    // 2-way unroll: two independent gathers in flight
    for (; j + 1 < e; j += 2) {
        int r0 = adj[j], r1 = adj[j + 1];
        float d0 = dinv[r0], d1 = dinv[r1];
        float2 v0 = ((const float2*)(xw + (size_t)r0 * D))[lane];
        float2 v1 = ((const float2*)(xw + (size_t)r1 * D))[lane];
        acc0 = fmaf(d0, v0.x, acc0);
        acc1 = fmaf(d0, v0.y, acc1);
        acc0 = fmaf(d1, v1.x, acc0);
        acc1 = fmaf(d1, v1.y, acc1);
    }
    if (j < e) {
        int r = adj[j];
        float dr = dinv[r];
        float2 v = ((const float2*)(xw + (size_t)r * D))[lane];
        acc0 = fmaf(dr, v.x, acc0);
        acc1 = fmaf(dr, v.y, acc1);
    }
    float2 bv = ((const float2*)bias)[lane];
    float o0 = fmaxf(fmaf(di, acc0, bv.x), 0.f);
    float o1 = fmaxf(fmaf(di, acc1, bv.y), 0.f);
    ((float2*)(hout + (size_t)i * D))[lane] = make_float2(o0, o1);
}

// ---------------- edge-classifier precompute ----------------
// P1[i] = h[i] @ Wfc[0:128, :] + bfc   (4 floats per node)
// P2[i] = h[i] @ Wfc[128:256, :]       (4 floats per node)
// Wfc accesses are wave-uniform -> compiler scalarizes to s_load.

__global__ __launch_bounds__(256) void pq_kernel(const float* __restrict__ h,
                                                 const float* __restrict__ Wfc,
                                                 const float* __restrict__ bfc,
                                                 float* __restrict__ P1,
                                                 float* __restrict__ P2, int n) {
    int i = blockIdx.x * blockDim.x + threadIdx.x;
    if (i >= n) return;
    const float4* hr = (const float4*)(h + (size_t)i * D);
    const float4* W4 = (const float4*)Wfc;   // 256 rows of float4
    float p0 = bfc[0], p1 = bfc[1], p2 = bfc[2], p3 = bfc[3];
    float q0 = 0.f, q1 = 0.f, q2 = 0.f, q3 = 0.f;
#pragma unroll 8
    for (int kk = 0; kk < 32; kk++) {
        float4 f = hr[kk];
#pragma unroll
        for (int j = 0; j < 4; j++) {
            float fv = (j == 0) ? f.x : (j == 1) ? f.y : (j == 2) ? f.z : f.w;
            int k = kk * 4 + j;
            float4 w1 = W4[k];         // uniform -> s_load
            float4 w2 = W4[128 + k];   // uniform -> s_load
            p0 = fmaf(fv, w1.x, p0); p1 = fmaf(fv, w1.y, p1);
            p2 = fmaf(fv, w1.z, p2); p3 = fmaf(fv, w1.w, p3);
            q0 = fmaf(fv, w2.x, q0); q1 = fmaf(fv, w2.y, q1);
            q2 = fmaf(fv, w2.z, q2); q3 = fmaf(fv, w2.w, q3);
        }
    }
    ((float4*)P1)[i] = make_float4(p0, p1, p2, p3);
    ((float4*)P2)[i] = make_float4(q0, q1, q2, q3);
}

// ---------------- edge classifier: one THREAD per edge ----------------

__global__ __launch_bounds__(256) void edge2_kernel(const int* __restrict__ row,
                                                    const int* __restrict__ col,
                                                    const float* __restrict__ P1,
                                                    const float* __restrict__ P2,
                                                    float* __restrict__ out, int E) {
    int e = blockIdx.x * blockDim.x + threadIdx.x;
    if (e >= E) return;
    int r = row[e], c = col[e];
    float4 a = ((const float4*)P1)[r];
    float4 b = ((const float4*)P2)[c];
    float sx = a.x + b.x, sy = a.y + b.y, sz = a.z + b.z, sw = a.w + b.w;
    float m = fmaxf(fmaxf(sx, sy), fmaxf(sz, sw));
    float e0 = expf(sx - m), e1 = expf(sy - m), e2 = expf(sz - m), e3 = expf(sw - m);
    float lse = m + logf(e0 + e1 + e2 + e3);
    *(float4*)(out + (size_t)e * 4) = make_float4(sx - lse, sy - lse, sz - lse, sw - lse);
}

// ---------------- launch ----------------

extern "C" void kernel_launch(void* const* d_in, const int* in_sizes, int n_in,
                              void* d_out, int out_size, void* d_ws, size_t ws_size,
                              hipStream_t stream) {
    const float* x   = (const float*)d_in[0];
    const int*   ei  = (const int*)d_in[1];
    const float* W1  = (const float*)d_in[2];
    const float* b1  = (const float*)d_in[3];
    const float* W2  = (const float*)d_in[4];
    const float* b2  = (const float*)d_in[5];
    const float* Wfc = (const float*)d_in[6];
    const float* bfc = (const float*)d_in[7];
    float* out = (float*)d_out;

    int n = in_sizes[0] / D;        // 50000
    int E = in_sizes[1] / 2;        // 600000
    const int* row = ei;            // edge_index[0]
    const int* col = ei + E;        // edge_index[1]

    // workspace layout (floats/ints)
    float* bufA = (float*)d_ws;                 // n*D  (xw scratch; later reused for P1/P2)
    float* bufB = bufA + (size_t)n * D;         // n*D  (h)
    int*   cnt  = (int*)(bufB + (size_t)n * D); // n
    int*   offs = cnt + n;                      // n+1
    int*   curs = offs + (n + 1);               // n
    int*   adj  = curs + n;                     // E
    float* dinv = (float*)(adj + E);            // n

    int nb_n = (n + 255) / 256;
    int nb_e = (E + 255) / 256;

    // CSR build
    init_kernel<<<nb_n, 256, 0, stream>>>(cnt, curs, n);
    count_kernel<<<nb_e, 256, 0, stream>>>(col, cnt, E);
    scan_kernel<<<1, 1024, 0, stream>>>(cnt, offs, n);
    fill_kernel<<<nb_e, 256, 0, stream>>>(row, col, offs, curs, adj, E);
    dinv_kernel<<<nb_n, 256, 0, stream>>>(cnt, dinv, n);

    dim3 gg(D / BN, (n + BM - 1) / BM);

    // layer 1
    gemm128_kernel<<<gg, 256, 0, stream>>>(x, W1, bufA, n);
    agg_kernel<<<(n + 3) / 4, 256, 0, stream>>>(bufA, adj, offs, dinv, b1, bufB, n);
    // layer 2
    gemm128_kernel<<<gg, 256, 0, stream>>>(bufB, W2, bufA, n);
    agg_kernel<<<(n + 3) / 4, 256, 0, stream>>>(bufA, adj, offs, dinv, b2, bufB, n);

    // edge classifier: precompute P1/P2 (reuse bufA — xw no longer needed)
    float* P1 = bufA;                // n*4
    float* P2 = bufA + (size_t)n * 4; // n*4
    pq_kernel<<<nb_n, 256, 0, stream>>>(bufB, Wfc, bfc, P1, P2, n);
    edge2_kernel<<<nb_e, 256, 0, stream>>>(row, col, P1, P2, out, E);
}

// Round 3
// 342.872 us; speedup vs baseline: 1.6557x; 1.1701x over previous
//
#include <hip/hip_runtime.h>
#include <math.h>

#define D 128          // feature dim (d_in = d_h = 128)
#define BM 64
#define BN 64
#define BK 16

#define SCAN_CHUNK 2048   // elements per block in the 3-phase scan

// ---------------- CSR build ----------------

__global__ void count_kernel(const int* col, int* cnt, int E) {
    int e = blockIdx.x * blockDim.x + threadIdx.x;
    if (e < E) atomicAdd(&cnt[col[e]], 1);
}

// Phase A: per-block sums over SCAN_CHUNK-element chunks (coalesced).
__global__ __launch_bounds__(256) void scanA_kernel(const int* __restrict__ cnt,
                                                    int* __restrict__ bsum, int n) {
    __shared__ int wsum[4];
    int b = blockIdx.x, t = threadIdx.x;
    int base = b * SCAN_CHUNK;
    int s = 0;
#pragma unroll
    for (int k = 0; k < SCAN_CHUNK / 256; k++) {
        int i = base + k * 256 + t;
        if (i < n) s += cnt[i];
    }
#pragma unroll
    for (int off = 32; off > 0; off >>= 1) s += __shfl_xor(s, off, 64);
    if ((t & 63) == 0) wsum[t >> 6] = s;
    __syncthreads();
    if (t == 0) bsum[b] = wsum[0] + wsum[1] + wsum[2] + wsum[3];
}

// Phase B: one wave scans the block sums -> exclusive bases + total (offs[n]).
__global__ __launch_bounds__(64) void scanB_kernel(const int* __restrict__ bsum,
                                                   int* __restrict__ bbase,
                                                   int* __restrict__ offs,
                                                   int nb, int n) {
    int t = threadIdx.x;
    int v = (t < nb) ? bsum[t] : 0;
    int inc = v;
#pragma unroll
    for (int off = 1; off < 64; off <<= 1) {
        int u = __shfl_up(inc, off, 64);
        if (t >= off) inc += u;
    }
    if (t < nb) bbase[t] = inc - v;
    if (t == nb - 1) offs[n] = inc;
}

// Phase C: per-block local exclusive scan (through LDS, coalesced both ways),
// fused with dinv computation.
__global__ __launch_bounds__(256) void scanC_kernel(const int* __restrict__ cnt,
                                                    const int* __restrict__ bbase,
                                                    int* __restrict__ offs,
                                                    float* __restrict__ dinv, int n) {
    __shared__ int stage[SCAN_CHUNK];
    __shared__ int res[SCAN_CHUNK];
    __shared__ int tsum[256];
    int b = blockIdx.x, t = threadIdx.x;
    int base = b * SCAN_CHUNK;
    // coalesced load into LDS (and fused dinv write)
#pragma unroll
    for (int k = 0; k < SCAN_CHUNK / 256; k++) {
        int i = base + k * 256 + t;
        int c = (i < n) ? cnt[i] : 0;
        stage[k * 256 + t] = c;
        if (i < n) dinv[i] = rsqrtf((float)c + 1.0f);
    }
    __syncthreads();
    // each thread scans its 8 contiguous elements
    int my = 0;
#pragma unroll
    for (int j = 0; j < 8; j++) my += stage[t * 8 + j];
    tsum[t] = my;
    __syncthreads();
    // Hillis-Steele inclusive scan over 256 thread sums
    for (int off = 1; off < 256; off <<= 1) {
        int v = (t >= off) ? tsum[t - off] : 0;
        __syncthreads();
        tsum[t] += v;
        __syncthreads();
    }
    int run = tsum[t] - my + bbase[b];   // exclusive base for this thread's span
#pragma unroll
    for (int j = 0; j < 8; j++) {
        res[t * 8 + j] = run;
        run += stage[t * 8 + j];
    }
    __syncthreads();
    // coalesced write of offs
#pragma unroll
    for (int k = 0; k < SCAN_CHUNK / 256; k++) {
        int i = base + k * 256 + t;
        if (i < n) offs[i] = res[k * 256 + t];
    }
}

__global__ void fill_kernel(const int* row, const int* col, const int* offs,
                            int* curs, int* adj, int E) {
    int e = blockIdx.x * blockDim.x + threadIdx.x;
    if (e < E) {
        int c = col[e];
        int p = atomicAdd(&curs[c], 1);
        adj[offs[c] + p] = row[e];
    }
}

// ---------------- GEMM: C[M x 128] = A[M x 128] @ W[128 x 128] ----------------

__global__ __launch_bounds__(256) void gemm128_kernel(const float* __restrict__ A,
                                                      const float* __restrict__ W,
                                                      float* __restrict__ C, int M) {
    __shared__ float As[BK][BM + 4];
    __shared__ float Bs[BK][BN + 4];
    int bm = blockIdx.y, bn = blockIdx.x;
    int t = threadIdx.x;
    int tc = t & 15, tr = t >> 4;

    int arow = t >> 2;   // 0..63
    int akq  = t & 3;    // k-quad
    int brow = t >> 4;   // 0..15 (k within tile)
    int bcq  = t & 15;   // col quad
    int grow = bm * BM + arow;

    float acc[4][4] = {};

    for (int k0 = 0; k0 < D; k0 += BK) {
        float4 av;
        if (grow < M)
            av = *(const float4*)(A + (size_t)grow * D + k0 + akq * 4);
        else
            av = make_float4(0.f, 0.f, 0.f, 0.f);
        As[akq * 4 + 0][arow] = av.x;
        As[akq * 4 + 1][arow] = av.y;
        As[akq * 4 + 2][arow] = av.z;
        As[akq * 4 + 3][arow] = av.w;

        float4 bv = *(const float4*)(W + (size_t)(k0 + brow) * D + bn * BN + bcq * 4);
        *(float4*)&Bs[brow][bcq * 4] = bv;
        __syncthreads();

#pragma unroll
        for (int kk = 0; kk < BK; kk++) {
            float4 a = *(const float4*)&As[kk][tr * 4];
            float4 b = *(const float4*)&Bs[kk][tc * 4];
            acc[0][0] += a.x * b.x; acc[0][1] += a.x * b.y; acc[0][2] += a.x * b.z; acc[0][3] += a.x * b.w;
            acc[1][0] += a.y * b.x; acc[1][1] += a.y * b.y; acc[1][2] += a.y * b.z; acc[1][3] += a.y * b.w;
            acc[2][0] += a.z * b.x; acc[2][1] += a.z * b.y; acc[2][2] += a.z * b.z; acc[2][3] += a.z * b.w;
            acc[3][0] += a.w * b.x; acc[3][1] += a.w * b.y; acc[3][2] += a.w * b.z; acc[3][3] += a.w * b.w;
        }
        __syncthreads();
    }

    int crow = bm * BM + tr * 4;
    int ccol = bn * BN + tc * 4;
#pragma unroll
    for (int r = 0; r < 4; r++) {
        if (crow + r < M) {
            float4 o = make_float4(acc[r][0], acc[r][1], acc[r][2], acc[r][3]);
            *(float4*)(C + (size_t)(crow + r) * D + ccol) = o;
        }
    }
}

// ---------------- aggregation: one wave per node ----------------

__global__ __launch_bounds__(256) void agg_kernel(const float* __restrict__ xw,
                                                  const int* __restrict__ adj,
                                                  const int* __restrict__ offs,
                                                  const float* __restrict__ dinv,
                                                  const float* __restrict__ bias,
                                                  float* __restrict__ hout, int n) {
    int wave = (int)((blockIdx.x * (size_t)blockDim.x + threadIdx.x) >> 6);
    int lane = threadIdx.x & 63;
    if (wave >= n) return;
    int i = wave;
    float di = dinv[i];
    float2 self = ((const float2*)(xw + (size_t)i * D))[lane];
    float acc0 = di * self.x;
    float acc1 = di * self.y;
    int s = offs[i], e = offs[i + 1];
    int j = s;
    for (; j + 1 < e; j += 2) {
        int r0 = adj[j], r1 = adj[j + 1];
        float d0 = dinv[r0], d1 = dinv[r1];
        float2 v0 = ((const float2*)(xw + (size_t)r0 * D))[lane];
        float2 v1 = ((const float2*)(xw + (size_t)r1 * D))[lane];
        acc0 = fmaf(d0, v0.x, acc0);
        acc1 = fmaf(d0, v0.y, acc1);
        acc0 = fmaf(d1, v1.x, acc0);
        acc1 = fmaf(d1, v1.y, acc1);
    }
    if (j < e) {
        int r = adj[j];
        float dr = dinv[r];
        float2 v = ((const float2*)(xw + (size_t)r * D))[lane];
        acc0 = fmaf(dr, v.x, acc0);
        acc1 = fmaf(dr, v.y, acc1);
    }
    float2 bv = ((const float2*)bias)[lane];
    float o0 = fmaxf(fmaf(di, acc0, bv.x), 0.f);
    float o1 = fmaxf(fmaf(di, acc1, bv.y), 0.f);
    ((float2*)(hout + (size_t)i * D))[lane] = make_float2(o0, o1);
}

// ---------------- edge-classifier precompute ----------------

__global__ __launch_bounds__(256) void pq_kernel(const float* __restrict__ h,
                                                 const float* __restrict__ Wfc,
                                                 const float* __restrict__ bfc,
                                                 float* __restrict__ P1,
                                                 float* __restrict__ P2, int n) {
    int i = blockIdx.x * blockDim.x + threadIdx.x;
    if (i >= n) return;
    const float4* hr = (const float4*)(h + (size_t)i * D);
    const float4* W4 = (const float4*)Wfc;   // 256 rows of float4
    float p0 = bfc[0], p1 = bfc[1], p2 = bfc[2], p3 = bfc[3];
    float q0 = 0.f, q1 = 0.f, q2 = 0.f, q3 = 0.f;
#pragma unroll 8
    for (int kk = 0; kk < 32; kk++) {
        float4 f = hr[kk];
#pragma unroll
        for (int j = 0; j < 4; j++) {
            float fv = (j == 0) ? f.x : (j == 1) ? f.y : (j == 2) ? f.z : f.w;
            int k = kk * 4 + j;
            float4 w1 = W4[k];         // uniform -> s_load
            float4 w2 = W4[128 + k];   // uniform -> s_load
            p0 = fmaf(fv, w1.x, p0); p1 = fmaf(fv, w1.y, p1);
            p2 = fmaf(fv, w1.z, p2); p3 = fmaf(fv, w1.w, p3);
            q0 = fmaf(fv, w2.x, q0); q1 = fmaf(fv, w2.y, q1);
            q2 = fmaf(fv, w2.z, q2); q3 = fmaf(fv, w2.w, q3);
        }
    }
    ((float4*)P1)[i] = make_float4(p0, p1, p2, p3);
    ((float4*)P2)[i] = make_float4(q0, q1, q2, q3);
}

// ---------------- edge classifier: one THREAD per edge ----------------

__global__ __launch_bounds__(256) void edge2_kernel(const int* __restrict__ row,
                                                    const int* __restrict__ col,
                                                    const float* __restrict__ P1,
                                                    const float* __restrict__ P2,
                                                    float* __restrict__ out, int E) {
    int e = blockIdx.x * blockDim.x + threadIdx.x;
    if (e >= E) return;
    int r = row[e], c = col[e];
    float4 a = ((const float4*)P1)[r];
    float4 b = ((const float4*)P2)[c];
    float sx = a.x + b.x, sy = a.y + b.y, sz = a.z + b.z, sw = a.w + b.w;
    float m = fmaxf(fmaxf(sx, sy), fmaxf(sz, sw));
    float e0 = expf(sx - m), e1 = expf(sy - m), e2 = expf(sz - m), e3 = expf(sw - m);
    float lse = m + logf(e0 + e1 + e2 + e3);
    *(float4*)(out + (size_t)e * 4) = make_float4(sx - lse, sy - lse, sz - lse, sw - lse);
}

// ---------------- launch ----------------

extern "C" void kernel_launch(void* const* d_in, const int* in_sizes, int n_in,
                              void* d_out, int out_size, void* d_ws, size_t ws_size,
                              hipStream_t stream) {
    const float* x   = (const float*)d_in[0];
    const int*   ei  = (const int*)d_in[1];
    const float* W1  = (const float*)d_in[2];
    const float* b1  = (const float*)d_in[3];
    const float* W2  = (const float*)d_in[4];
    const float* b2  = (const float*)d_in[5];
    const float* Wfc = (const float*)d_in[6];
    const float* bfc = (const float*)d_in[7];
    float* out = (float*)d_out;

    int n = in_sizes[0] / D;        // 50000
    int E = in_sizes[1] / 2;        // 600000
    const int* row = ei;            // edge_index[0]
    const int* col = ei + E;        // edge_index[1]

    int nbScan = (n + SCAN_CHUNK - 1) / SCAN_CHUNK;   // 25

    // workspace layout
    float* bufA  = (float*)d_ws;                  // n*D
    float* bufB  = bufA + (size_t)n * D;          // n*D
    int*   cnt   = (int*)(bufB + (size_t)n * D);  // n   } adjacent for one memset
    int*   curs  = cnt + n;                       // n   }
    int*   offs  = curs + n;                      // n+1
    int*   bsum  = offs + (n + 1);                // nbScan
    int*   bbase = bsum + nbScan;                 // nbScan
    int*   adj   = bbase + nbScan;                // E
    float* dinv  = (float*)(adj + E);             // n

    int nb_n = (n + 255) / 256;
    int nb_e = (E + 255) / 256;

    // CSR build
    hipMemsetAsync(cnt, 0, (size_t)2 * n * sizeof(int), stream);   // cnt + curs
    count_kernel<<<nb_e, 256, 0, stream>>>(col, cnt, E);
    scanA_kernel<<<nbScan, 256, 0, stream>>>(cnt, bsum, n);
    scanB_kernel<<<1, 64, 0, stream>>>(bsum, bbase, offs, nbScan, n);
    scanC_kernel<<<nbScan, 256, 0, stream>>>(cnt, bbase, offs, dinv, n);
    fill_kernel<<<nb_e, 256, 0, stream>>>(row, col, offs, curs, adj, E);

    dim3 gg(D / BN, (n + BM - 1) / BM);

    // layer 1
    gemm128_kernel<<<gg, 256, 0, stream>>>(x, W1, bufA, n);
    agg_kernel<<<(n + 3) / 4, 256, 0, stream>>>(bufA, adj, offs, dinv, b1, bufB, n);
    // layer 2
    gemm128_kernel<<<gg, 256, 0, stream>>>(bufB, W2, bufA, n);
    agg_kernel<<<(n + 3) / 4, 256, 0, stream>>>(bufA, adj, offs, dinv, b2, bufB, n);

    // edge classifier
    float* P1 = bufA;                 // n*4
    float* P2 = bufA + (size_t)n * 4; // n*4
    pq_kernel<<<nb_n, 256, 0, stream>>>(bufB, Wfc, bfc, P1, P2, n);
    edge2_kernel<<<nb_e, 256, 0, stream>>>(row, col, P1, P2, out, E);
}

// Round 4
// 298.046 us; speedup vs baseline: 1.9048x; 1.1504x over previous
//
#include <hip/hip_runtime.h>
#include <math.h>
#include <stdint.h>

#define D 128          // feature dim (d_in = d_h = 128)
#define BM 64
#define BN 64
#define BK 16

#define SCAN_CHUNK 2048   // elements per block in the 3-phase scan

// bf16 round-to-nearest-even
static __device__ __forceinline__ uint16_t f2bf(float f) {
    uint32_t u = __float_as_uint(f);
    u = (u + 0x7fff + ((u >> 16) & 1)) >> 16;
    return (uint16_t)u;
}
static __device__ __forceinline__ float bf_lo(uint32_t u) { return __uint_as_float(u << 16); }
static __device__ __forceinline__ float bf_hi(uint32_t u) { return __uint_as_float(u & 0xffff0000u); }

// ---------------- CSR build ----------------

__global__ void count_kernel(const int* col, int* cnt, int E) {
    int e = blockIdx.x * blockDim.x + threadIdx.x;
    if (e < E) atomicAdd(&cnt[col[e]], 1);
}

// Phase A: per-block sums over SCAN_CHUNK-element chunks (coalesced).
__global__ __launch_bounds__(256) void scanA_kernel(const int* __restrict__ cnt,
                                                    int* __restrict__ bsum, int n) {
    __shared__ int wsum[4];
    int b = blockIdx.x, t = threadIdx.x;
    int base = b * SCAN_CHUNK;
    int s = 0;
#pragma unroll
    for (int k = 0; k < SCAN_CHUNK / 256; k++) {
        int i = base + k * 256 + t;
        if (i < n) s += cnt[i];
    }
#pragma unroll
    for (int off = 32; off > 0; off >>= 1) s += __shfl_xor(s, off, 64);
    if ((t & 63) == 0) wsum[t >> 6] = s;
    __syncthreads();
    if (t == 0) bsum[b] = wsum[0] + wsum[1] + wsum[2] + wsum[3];
}

// Phase B: one wave scans the block sums -> exclusive bases + total (offs[n]).
__global__ __launch_bounds__(64) void scanB_kernel(const int* __restrict__ bsum,
                                                   int* __restrict__ bbase,
                                                   int* __restrict__ offs,
                                                   int nb, int n) {
    int t = threadIdx.x;
    int v = (t < nb) ? bsum[t] : 0;
    int inc = v;
#pragma unroll
    for (int off = 1; off < 64; off <<= 1) {
        int u = __shfl_up(inc, off, 64);
        if (t >= off) inc += u;
    }
    if (t < nb) bbase[t] = inc - v;
    if (t == nb - 1) offs[n] = inc;
}

// Phase C: per-block local exclusive scan, fused with dinv computation.
__global__ __launch_bounds__(256) void scanC_kernel(const int* __restrict__ cnt,
                                                    const int* __restrict__ bbase,
                                                    int* __restrict__ offs,
                                                    float* __restrict__ dinv, int n) {
    __shared__ int stage[SCAN_CHUNK];
    __shared__ int res[SCAN_CHUNK];
    __shared__ int tsum[256];
    int b = blockIdx.x, t = threadIdx.x;
    int base = b * SCAN_CHUNK;
#pragma unroll
    for (int k = 0; k < SCAN_CHUNK / 256; k++) {
        int i = base + k * 256 + t;
        int c = (i < n) ? cnt[i] : 0;
        stage[k * 256 + t] = c;
        if (i < n) dinv[i] = rsqrtf((float)c + 1.0f);
    }
    __syncthreads();
    int my = 0;
#pragma unroll
    for (int j = 0; j < 8; j++) my += stage[t * 8 + j];
    tsum[t] = my;
    __syncthreads();
    for (int off = 1; off < 256; off <<= 1) {
        int v = (t >= off) ? tsum[t - off] : 0;
        __syncthreads();
        tsum[t] += v;
        __syncthreads();
    }
    int run = tsum[t] - my + bbase[b];
#pragma unroll
    for (int j = 0; j < 8; j++) {
        res[t * 8 + j] = run;
        run += stage[t * 8 + j];
    }
    __syncthreads();
#pragma unroll
    for (int k = 0; k < SCAN_CHUNK / 256; k++) {
        int i = base + k * 256 + t;
        if (i < n) offs[i] = res[k * 256 + t];
    }
}

__global__ void fill_kernel(const int* row, const int* col, const int* offs,
                            int* curs, int* adj, int E) {
    int e = blockIdx.x * blockDim.x + threadIdx.x;
    if (e < E) {
        int c = col[e];
        int p = atomicAdd(&curs[c], 1);
        adj[offs[c] + p] = row[e];
    }
}

// ---------------- GEMM: xwb[i,:] = bf16( dinv[i] * (A[i,:] @ W) ) ----------------

__global__ __launch_bounds__(256) void gemm128_kernel(const float* __restrict__ A,
                                                      const float* __restrict__ W,
                                                      const float* __restrict__ dinv,
                                                      uint16_t* __restrict__ Cb, int M) {
    __shared__ float As[BK][BM + 4];
    __shared__ float Bs[BK][BN + 4];
    int bm = blockIdx.y, bn = blockIdx.x;
    int t = threadIdx.x;
    int tc = t & 15, tr = t >> 4;

    int arow = t >> 2;   // 0..63
    int akq  = t & 3;    // k-quad
    int brow = t >> 4;   // 0..15 (k within tile)
    int bcq  = t & 15;   // col quad
    int grow = bm * BM + arow;

    float acc[4][4] = {};

    for (int k0 = 0; k0 < D; k0 += BK) {
        float4 av;
        if (grow < M)
            av = *(const float4*)(A + (size_t)grow * D + k0 + akq * 4);
        else
            av = make_float4(0.f, 0.f, 0.f, 0.f);
        As[akq * 4 + 0][arow] = av.x;
        As[akq * 4 + 1][arow] = av.y;
        As[akq * 4 + 2][arow] = av.z;
        As[akq * 4 + 3][arow] = av.w;

        float4 bv = *(const float4*)(W + (size_t)(k0 + brow) * D + bn * BN + bcq * 4);
        *(float4*)&Bs[brow][bcq * 4] = bv;
        __syncthreads();

#pragma unroll
        for (int kk = 0; kk < BK; kk++) {
            float4 a = *(const float4*)&As[kk][tr * 4];
            float4 b = *(const float4*)&Bs[kk][tc * 4];
            acc[0][0] += a.x * b.x; acc[0][1] += a.x * b.y; acc[0][2] += a.x * b.z; acc[0][3] += a.x * b.w;
            acc[1][0] += a.y * b.x; acc[1][1] += a.y * b.y; acc[1][2] += a.y * b.z; acc[1][3] += a.y * b.w;
            acc[2][0] += a.z * b.x; acc[2][1] += a.z * b.y; acc[2][2] += a.z * b.z; acc[2][3] += a.z * b.w;
            acc[3][0] += a.w * b.x; acc[3][1] += a.w * b.y; acc[3][2] += a.w * b.z; acc[3][3] += a.w * b.w;
        }
        __syncthreads();
    }

    int crow = bm * BM + tr * 4;
    int ccol = bn * BN + tc * 4;
#pragma unroll
    for (int r = 0; r < 4; r++) {
        int gr = crow + r;
        if (gr < M) {
            float di = dinv[gr];
            uint32_t lo = (uint32_t)f2bf(di * acc[r][0]) | ((uint32_t)f2bf(di * acc[r][1]) << 16);
            uint32_t hi = (uint32_t)f2bf(di * acc[r][2]) | ((uint32_t)f2bf(di * acc[r][3]) << 16);
            uint2 o = make_uint2(lo, hi);
            *(uint2*)(Cb + (size_t)gr * D + ccol) = o;
        }
    }
}

// ---------------- aggregation: one wave per node ----------------
// xwb rows are already dinv-prescaled bf16. h[i] = relu(b + dinv[i]*Σ_{r∈in(i)∪{i}} xwb[r])

__global__ __launch_bounds__(256) void agg_kernel(const uint32_t* __restrict__ xwb,
                                                  const int* __restrict__ adj,
                                                  const int* __restrict__ offs,
                                                  const float* __restrict__ dinv,
                                                  const float* __restrict__ bias,
                                                  float* __restrict__ hout, int n) {
    int wave = (int)((blockIdx.x * (size_t)blockDim.x + threadIdx.x) >> 6);
    int lane = threadIdx.x & 63;
    if (wave >= n) return;
    int i = wave;
    uint32_t su = xwb[(size_t)i * (D / 2) + lane];
    float acc0 = bf_lo(su);
    float acc1 = bf_hi(su);
    int s = offs[i], e = offs[i + 1];
    int j = s;
    // 4-way unroll: four independent gathers in flight
    for (; j + 3 < e; j += 4) {
        int r0 = adj[j], r1 = adj[j + 1], r2 = adj[j + 2], r3 = adj[j + 3];
        uint32_t u0 = xwb[(size_t)r0 * (D / 2) + lane];
        uint32_t u1 = xwb[(size_t)r1 * (D / 2) + lane];
        uint32_t u2 = xwb[(size_t)r2 * (D / 2) + lane];
        uint32_t u3 = xwb[(size_t)r3 * (D / 2) + lane];
        acc0 += bf_lo(u0); acc1 += bf_hi(u0);
        acc0 += bf_lo(u1); acc1 += bf_hi(u1);
        acc0 += bf_lo(u2); acc1 += bf_hi(u2);
        acc0 += bf_lo(u3); acc1 += bf_hi(u3);
    }
    for (; j < e; j++) {
        int r = adj[j];
        uint32_t u = xwb[(size_t)r * (D / 2) + lane];
        acc0 += bf_lo(u); acc1 += bf_hi(u);
    }
    float di = dinv[i];
    float2 bv = ((const float2*)bias)[lane];
    float o0 = fmaxf(fmaf(di, acc0, bv.x), 0.f);
    float o1 = fmaxf(fmaf(di, acc1, bv.y), 0.f);
    ((float2*)(hout + (size_t)i * D))[lane] = make_float2(o0, o1);
}

// ---------------- edge-classifier precompute ----------------

__global__ __launch_bounds__(256) void pq_kernel(const float* __restrict__ h,
                                                 const float* __restrict__ Wfc,
                                                 const float* __restrict__ bfc,
                                                 float* __restrict__ P1,
                                                 float* __restrict__ P2, int n) {
    int i = blockIdx.x * blockDim.x + threadIdx.x;
    if (i >= n) return;
    const float4* hr = (const float4*)(h + (size_t)i * D);
    const float4* W4 = (const float4*)Wfc;   // 256 rows of float4
    float p0 = bfc[0], p1 = bfc[1], p2 = bfc[2], p3 = bfc[3];
    float q0 = 0.f, q1 = 0.f, q2 = 0.f, q3 = 0.f;
#pragma unroll 8
    for (int kk = 0; kk < 32; kk++) {
        float4 f = hr[kk];
#pragma unroll
        for (int j = 0; j < 4; j++) {
            float fv = (j == 0) ? f.x : (j == 1) ? f.y : (j == 2) ? f.z : f.w;
            int k = kk * 4 + j;
            float4 w1 = W4[k];         // uniform -> s_load
            float4 w2 = W4[128 + k];   // uniform -> s_load
            p0 = fmaf(fv, w1.x, p0); p1 = fmaf(fv, w1.y, p1);
            p2 = fmaf(fv, w1.z, p2); p3 = fmaf(fv, w1.w, p3);
            q0 = fmaf(fv, w2.x, q0); q1 = fmaf(fv, w2.y, q1);
            q2 = fmaf(fv, w2.z, q2); q3 = fmaf(fv, w2.w, q3);
        }
    }
    ((float4*)P1)[i] = make_float4(p0, p1, p2, p3);
    ((float4*)P2)[i] = make_float4(q0, q1, q2, q3);
}

// ---------------- edge classifier: one THREAD per edge ----------------

__global__ __launch_bounds__(256) void edge2_kernel(const int* __restrict__ row,
                                                    const int* __restrict__ col,
                                                    const float* __restrict__ P1,
                                                    const float* __restrict__ P2,
                                                    float* __restrict__ out, int E) {
    int e = blockIdx.x * blockDim.x + threadIdx.x;
    if (e >= E) return;
    int r = row[e], c = col[e];
    float4 a = ((const float4*)P1)[r];
    float4 b = ((const float4*)P2)[c];
    float sx = a.x + b.x, sy = a.y + b.y, sz = a.z + b.z, sw = a.w + b.w;
    float m = fmaxf(fmaxf(sx, sy), fmaxf(sz, sw));
    float e0 = expf(sx - m), e1 = expf(sy - m), e2 = expf(sz - m), e3 = expf(sw - m);
    float lse = m + logf(e0 + e1 + e2 + e3);
    *(float4*)(out + (size_t)e * 4) = make_float4(sx - lse, sy - lse, sz - lse, sw - lse);
}

// ---------------- launch ----------------

extern "C" void kernel_launch(void* const* d_in, const int* in_sizes, int n_in,
                              void* d_out, int out_size, void* d_ws, size_t ws_size,
                              hipStream_t stream) {
    const float* x   = (const float*)d_in[0];
    const int*   ei  = (const int*)d_in[1];
    const float* W1  = (const float*)d_in[2];
    const float* b1  = (const float*)d_in[3];
    const float* W2  = (const float*)d_in[4];
    const float* b2  = (const float*)d_in[5];
    const float* Wfc = (const float*)d_in[6];
    const float* bfc = (const float*)d_in[7];
    float* out = (float*)d_out;

    int n = in_sizes[0] / D;        // 50000
    int E = in_sizes[1] / 2;        // 600000
    const int* row = ei;            // edge_index[0]
    const int* col = ei + E;        // edge_index[1]

    int nbScan = (n + SCAN_CHUNK - 1) / SCAN_CHUNK;   // 25

    // workspace layout
    uint16_t* xwb  = (uint16_t*)d_ws;                    // n*D bf16 (dinv-prescaled xW)
    float*    h    = (float*)(xwb + (size_t)n * D);      // n*D f32
    int*      cnt  = (int*)(h + (size_t)n * D);          // n   } adjacent for one memset
    int*      curs = cnt + n;                            // n   }
    int*      offs = curs + n;                           // n+1
    int*      bsum = offs + (n + 1);                     // nbScan
    int*      bbase= bsum + nbScan;                      // nbScan
    int*      adj  = bbase + nbScan;                     // E
    float*    dinv = (float*)(adj + E);                  // n

    int nb_n = (n + 255) / 256;
    int nb_e = (E + 255) / 256;

    // CSR build
    hipMemsetAsync(cnt, 0, (size_t)2 * n * sizeof(int), stream);   // cnt + curs
    count_kernel<<<nb_e, 256, 0, stream>>>(col, cnt, E);
    scanA_kernel<<<nbScan, 256, 0, stream>>>(cnt, bsum, n);
    scanB_kernel<<<1, 64, 0, stream>>>(bsum, bbase, offs, nbScan, n);
    scanC_kernel<<<nbScan, 256, 0, stream>>>(cnt, bbase, offs, dinv, n);
    fill_kernel<<<nb_e, 256, 0, stream>>>(row, col, offs, curs, adj, E);

    dim3 gg(D / BN, (n + BM - 1) / BM);

    // layer 1
    gemm128_kernel<<<gg, 256, 0, stream>>>(x, W1, dinv, xwb, n);
    agg_kernel<<<(n + 3) / 4, 256, 0, stream>>>((const uint32_t*)xwb, adj, offs, dinv, b1, h, n);
    // layer 2
    gemm128_kernel<<<gg, 256, 0, stream>>>(h, W2, dinv, xwb, n);
    agg_kernel<<<(n + 3) / 4, 256, 0, stream>>>((const uint32_t*)xwb, adj, offs, dinv, b2, h, n);

    // edge classifier (reuse xwb region for P1/P2)
    float* P1 = (float*)xwb;          // n*4
    float* P2 = P1 + (size_t)n * 4;   // n*4
    pq_kernel<<<nb_n, 256, 0, stream>>>(h, Wfc, bfc, P1, P2, n);
    edge2_kernel<<<nb_e, 256, 0, stream>>>(row, col, P1, P2, out, E);
}

// Round 5
// 270.358 us; speedup vs baseline: 2.0998x; 1.1024x over previous
//
#include <hip/hip_runtime.h>
#include <math.h>
#include <stdint.h>

#define D 128          // feature dim (d_in = d_h = 128)
#define SCAN_CHUNK 2048
#define LDA 136        // LDS row stride in shorts (+8 pad: 16-way -> 2-way bank conflict)

typedef __attribute__((ext_vector_type(8))) short v8s;   // 8 bf16 (4 VGPRs)
typedef __attribute__((ext_vector_type(4))) float v4f;   // MFMA accumulator

// bf16 round-to-nearest-even
static __device__ __forceinline__ uint16_t f2bf(float f) {
    uint32_t u = __float_as_uint(f);
    u = (u + 0x7fff + ((u >> 16) & 1)) >> 16;
    return (uint16_t)u;
}
static __device__ __forceinline__ float bf2f(uint16_t h) { return __uint_as_float((uint32_t)h << 16); }
static __device__ __forceinline__ float bf_lo(uint32_t u) { return __uint_as_float(u << 16); }
static __device__ __forceinline__ float bf_hi(uint32_t u) { return __uint_as_float(u & 0xffff0000u); }

// ---------------- CSR build ----------------

__global__ void count_kernel(const int* col, int* cnt, int E) {
    int e = blockIdx.x * blockDim.x + threadIdx.x;
    if (e < E) atomicAdd(&cnt[col[e]], 1);
}

__global__ __launch_bounds__(256) void scanA_kernel(const int* __restrict__ cnt,
                                                    int* __restrict__ bsum, int n) {
    __shared__ int wsum[4];
    int b = blockIdx.x, t = threadIdx.x;
    int base = b * SCAN_CHUNK;
    int s = 0;
#pragma unroll
    for (int k = 0; k < SCAN_CHUNK / 256; k++) {
        int i = base + k * 256 + t;
        if (i < n) s += cnt[i];
    }
#pragma unroll
    for (int off = 32; off > 0; off >>= 1) s += __shfl_xor(s, off, 64);
    if ((t & 63) == 0) wsum[t >> 6] = s;
    __syncthreads();
    if (t == 0) bsum[b] = wsum[0] + wsum[1] + wsum[2] + wsum[3];
}

__global__ __launch_bounds__(64) void scanB_kernel(const int* __restrict__ bsum,
                                                   int* __restrict__ bbase,
                                                   int* __restrict__ offs,
                                                   int nb, int n) {
    int t = threadIdx.x;
    int v = (t < nb) ? bsum[t] : 0;
    int inc = v;
#pragma unroll
    for (int off = 1; off < 64; off <<= 1) {
        int u = __shfl_up(inc, off, 64);
        if (t >= off) inc += u;
    }
    if (t < nb) bbase[t] = inc - v;
    if (t == nb - 1) offs[n] = inc;
}

__global__ __launch_bounds__(256) void scanC_kernel(const int* __restrict__ cnt,
                                                    const int* __restrict__ bbase,
                                                    int* __restrict__ offs,
                                                    float* __restrict__ dinv, int n) {
    __shared__ int stage[SCAN_CHUNK];
    __shared__ int res[SCAN_CHUNK];
    __shared__ int tsum[256];
    int b = blockIdx.x, t = threadIdx.x;
    int base = b * SCAN_CHUNK;
#pragma unroll
    for (int k = 0; k < SCAN_CHUNK / 256; k++) {
        int i = base + k * 256 + t;
        int c = (i < n) ? cnt[i] : 0;
        stage[k * 256 + t] = c;
        if (i < n) dinv[i] = rsqrtf((float)c + 1.0f);
    }
    __syncthreads();
    int my = 0;
#pragma unroll
    for (int j = 0; j < 8; j++) my += stage[t * 8 + j];
    tsum[t] = my;
    __syncthreads();
    for (int off = 1; off < 256; off <<= 1) {
        int v = (t >= off) ? tsum[t - off] : 0;
        __syncthreads();
        tsum[t] += v;
        __syncthreads();
    }
    int run = tsum[t] - my + bbase[b];
#pragma unroll
    for (int j = 0; j < 8; j++) {
        res[t * 8 + j] = run;
        run += stage[t * 8 + j];
    }
    __syncthreads();
#pragma unroll
    for (int k = 0; k < SCAN_CHUNK / 256; k++) {
        int i = base + k * 256 + t;
        if (i < n) offs[i] = res[k * 256 + t];
    }
}

__global__ void fill_kernel(const int* row, const int* col, const int* offs,
                            int* curs, int* adj, int E) {
    int e = blockIdx.x * blockDim.x + threadIdx.x;
    if (e < E) {
        int c = col[e];
        int p = atomicAdd(&curs[c], 1);
        adj[offs[c] + p] = row[e];
    }
}

// ---------------- W pack: split fp32 W[128][128] into bf16 hi/lo in B-frag layout ----
// layout: frag f = kstep*8 + tile (0..31); element ((f*64)+lane)*8 + j
// maps to W[k = kstep*32 + (lane>>4)*8 + j][nn = tile*16 + (lane&15)]

__global__ __launch_bounds__(256) void packw_kernel(const float* __restrict__ W1,
                                                    const float* __restrict__ W2,
                                                    uint16_t* __restrict__ Wh,
                                                    uint16_t* __restrict__ Wl) {
    int i = blockIdx.x * blockDim.x + threadIdx.x;   // 0 .. 2*16384-1
    int layer = i >> 14;
    int li = i & 16383;
    int j = li & 7, lane = (li >> 3) & 63, f = li >> 9;
    int kstep = f >> 3, tile = f & 7;
    int k = kstep * 32 + ((lane >> 4) * 8) + j;
    int nn = tile * 16 + (lane & 15);
    const float* W = layer ? W2 : W1;
    float v = W[k * 128 + nn];
    uint16_t h = f2bf(v);
    uint16_t l = f2bf(v - bf2f(h));
    Wh[i] = h;
    Wl[i] = l;
}

// ---------------- MFMA GEMM: xwb[i,:] = bf16( dinv[i] * (A[i,:] @ W) ) ----------------
// split-bf16 (Markidis): A = Ah + Al, W = Wh + Wl; A@W ≈ Ah@Wh + Ah@Wl + Al@Wh

__global__ __launch_bounds__(256) void gemm_mfma_kernel(const float* __restrict__ A,
                                                        const uint16_t* __restrict__ Wph,
                                                        const uint16_t* __restrict__ Wpl,
                                                        const float* __restrict__ dinv,
                                                        uint16_t* __restrict__ Cb, int M) {
    __shared__ uint16_t Ah[64][LDA];
    __shared__ uint16_t Al[64][LDA];
    int t = threadIdx.x;
    int base_row = blockIdx.x * 64;

    // stage 64 rows x 128 K: fp32 -> bf16 hi/lo (coalesced float4 loads)
#pragma unroll
    for (int kk = 0; kk < 8; kk++) {
        int idx = kk * 256 + t;        // 0..2047
        int r = idx >> 5;              // 0..63
        int c4 = idx & 31;             // float4 col
        int gr = base_row + r;
        float4 f = (gr < M) ? *(const float4*)(A + (size_t)gr * D + c4 * 4)
                            : make_float4(0.f, 0.f, 0.f, 0.f);
        uint16_t h0 = f2bf(f.x), h1 = f2bf(f.y), h2 = f2bf(f.z), h3 = f2bf(f.w);
        uint16_t l0 = f2bf(f.x - bf2f(h0)), l1 = f2bf(f.y - bf2f(h1));
        uint16_t l2 = f2bf(f.z - bf2f(h2)), l3 = f2bf(f.w - bf2f(h3));
        *(ushort4*)&Ah[r][c4 * 4] = make_ushort4(h0, h1, h2, h3);
        *(ushort4*)&Al[r][c4 * 4] = make_ushort4(l0, l1, l2, l3);
    }
    __syncthreads();

    int lane = t & 63, w = t >> 6;
    int m_l = lane & 15, quad = lane >> 4;
    int arow = w * 16 + m_l;

    v4f acc[8];
#pragma unroll
    for (int i = 0; i < 8; i++) acc[i] = (v4f){0.f, 0.f, 0.f, 0.f};

#pragma unroll
    for (int ks = 0; ks < 4; ks++) {
        v8s ah = *(const v8s*)&Ah[arow][ks * 32 + quad * 8];
        v8s al = *(const v8s*)&Al[arow][ks * 32 + quad * 8];
#pragma unroll
        for (int ti = 0; ti < 8; ti++) {
            int f = ks * 8 + ti;
            v8s bh = *(const v8s*)(Wph + ((size_t)(f * 64 + lane)) * 8);
            v8s bl = *(const v8s*)(Wpl + ((size_t)(f * 64 + lane)) * 8);
            acc[ti] = __builtin_amdgcn_mfma_f32_16x16x32_bf16(al, bh, acc[ti], 0, 0, 0);
            acc[ti] = __builtin_amdgcn_mfma_f32_16x16x32_bf16(ah, bl, acc[ti], 0, 0, 0);
            acc[ti] = __builtin_amdgcn_mfma_f32_16x16x32_bf16(ah, bh, acc[ti], 0, 0, 0);
        }
    }

    // epilogue: C/D layout col = lane&15, row = quad*4 + reg (verified m89)
    int rbase = base_row + w * 16 + quad * 4;
#pragma unroll
    for (int reg = 0; reg < 4; reg++) {
        int gr = rbase + reg;
        if (gr < M) {
            float di = dinv[gr];
#pragma unroll
            for (int ti = 0; ti < 8; ti++) {
                Cb[(size_t)gr * D + ti * 16 + m_l] = f2bf(di * acc[ti][reg]);
            }
        }
    }
}

// ---------------- aggregation: one wave per node ----------------

__global__ __launch_bounds__(256) void agg_kernel(const uint32_t* __restrict__ xwb,
                                                  const int* __restrict__ adj,
                                                  const int* __restrict__ offs,
                                                  const float* __restrict__ dinv,
                                                  const float* __restrict__ bias,
                                                  float* __restrict__ hout, int n) {
    int wave = (int)((blockIdx.x * (size_t)blockDim.x + threadIdx.x) >> 6);
    int lane = threadIdx.x & 63;
    if (wave >= n) return;
    int i = wave;
    uint32_t su = xwb[(size_t)i * (D / 2) + lane];
    float acc0 = bf_lo(su);
    float acc1 = bf_hi(su);
    int s = offs[i], e = offs[i + 1];
    int j = s;
    for (; j + 3 < e; j += 4) {
        int r0 = adj[j], r1 = adj[j + 1], r2 = adj[j + 2], r3 = adj[j + 3];
        uint32_t u0 = xwb[(size_t)r0 * (D / 2) + lane];
        uint32_t u1 = xwb[(size_t)r1 * (D / 2) + lane];
        uint32_t u2 = xwb[(size_t)r2 * (D / 2) + lane];
        uint32_t u3 = xwb[(size_t)r3 * (D / 2) + lane];
        acc0 += bf_lo(u0); acc1 += bf_hi(u0);
        acc0 += bf_lo(u1); acc1 += bf_hi(u1);
        acc0 += bf_lo(u2); acc1 += bf_hi(u2);
        acc0 += bf_lo(u3); acc1 += bf_hi(u3);
    }
    for (; j < e; j++) {
        int r = adj[j];
        uint32_t u = xwb[(size_t)r * (D / 2) + lane];
        acc0 += bf_lo(u); acc1 += bf_hi(u);
    }
    float di = dinv[i];
    float2 bv = ((const float2*)bias)[lane];
    float o0 = fmaxf(fmaf(di, acc0, bv.x), 0.f);
    float o1 = fmaxf(fmaf(di, acc1, bv.y), 0.f);
    ((float2*)(hout + (size_t)i * D))[lane] = make_float2(o0, o1);
}

// ---------------- edge-classifier precompute ----------------

__global__ __launch_bounds__(256) void pq_kernel(const float* __restrict__ h,
                                                 const float* __restrict__ Wfc,
                                                 const float* __restrict__ bfc,
                                                 float* __restrict__ P1,
                                                 float* __restrict__ P2, int n) {
    int i = blockIdx.x * blockDim.x + threadIdx.x;
    if (i >= n) return;
    const float4* hr = (const float4*)(h + (size_t)i * D);
    const float4* W4 = (const float4*)Wfc;
    float p0 = bfc[0], p1 = bfc[1], p2 = bfc[2], p3 = bfc[3];
    float q0 = 0.f, q1 = 0.f, q2 = 0.f, q3 = 0.f;
#pragma unroll 8
    for (int kk = 0; kk < 32; kk++) {
        float4 f = hr[kk];
#pragma unroll
        for (int j = 0; j < 4; j++) {
            float fv = (j == 0) ? f.x : (j == 1) ? f.y : (j == 2) ? f.z : f.w;
            int k = kk * 4 + j;
            float4 w1 = W4[k];
            float4 w2 = W4[128 + k];
            p0 = fmaf(fv, w1.x, p0); p1 = fmaf(fv, w1.y, p1);
            p2 = fmaf(fv, w1.z, p2); p3 = fmaf(fv, w1.w, p3);
            q0 = fmaf(fv, w2.x, q0); q1 = fmaf(fv, w2.y, q1);
            q2 = fmaf(fv, w2.z, q2); q3 = fmaf(fv, w2.w, q3);
        }
    }
    ((float4*)P1)[i] = make_float4(p0, p1, p2, p3);
    ((float4*)P2)[i] = make_float4(q0, q1, q2, q3);
}

// ---------------- edge classifier: one THREAD per edge ----------------

__global__ __launch_bounds__(256) void edge2_kernel(const int* __restrict__ row,
                                                    const int* __restrict__ col,
                                                    const float* __restrict__ P1,
                                                    const float* __restrict__ P2,
                                                    float* __restrict__ out, int E) {
    int e = blockIdx.x * blockDim.x + threadIdx.x;
    if (e >= E) return;
    int r = row[e], c = col[e];
    float4 a = ((const float4*)P1)[r];
    float4 b = ((const float4*)P2)[c];
    float sx = a.x + b.x, sy = a.y + b.y, sz = a.z + b.z, sw = a.w + b.w;
    float m = fmaxf(fmaxf(sx, sy), fmaxf(sz, sw));
    float e0 = expf(sx - m), e1 = expf(sy - m), e2 = expf(sz - m), e3 = expf(sw - m);
    float lse = m + logf(e0 + e1 + e2 + e3);
    *(float4*)(out + (size_t)e * 4) = make_float4(sx - lse, sy - lse, sz - lse, sw - lse);
}

// ---------------- launch ----------------

extern "C" void kernel_launch(void* const* d_in, const int* in_sizes, int n_in,
                              void* d_out, int out_size, void* d_ws, size_t ws_size,
                              hipStream_t stream) {
    const float* x   = (const float*)d_in[0];
    const int*   ei  = (const int*)d_in[1];
    const float* W1  = (const float*)d_in[2];
    const float* b1  = (const float*)d_in[3];
    const float* W2  = (const float*)d_in[4];
    const float* b2  = (const float*)d_in[5];
    const float* Wfc = (const float*)d_in[6];
    const float* bfc = (const float*)d_in[7];
    float* out = (float*)d_out;

    int n = in_sizes[0] / D;        // 50000
    int E = in_sizes[1] / 2;        // 600000
    const int* row = ei;            // edge_index[0]
    const int* col = ei + E;        // edge_index[1]

    int nbScan = (n + SCAN_CHUNK - 1) / SCAN_CHUNK;   // 25

    // workspace layout
    uint16_t* xwb  = (uint16_t*)d_ws;                    // n*D bf16 (dinv-prescaled xW)
    float*    h    = (float*)(xwb + (size_t)n * D);      // n*D f32
    int*      cnt  = (int*)(h + (size_t)n * D);          // n   } adjacent for one memset
    int*      curs = cnt + n;                            // n   }
    int*      offs = curs + n;                           // n+1
    int*      bsum = offs + (n + 1);                     // nbScan
    int*      bbase= bsum + nbScan;                      // nbScan
    int*      adj  = bbase + nbScan;                     // E
    float*    dinv = (float*)(adj + E);                  // n
    uint16_t* Wph  = (uint16_t*)(dinv + n);              // 2*16384 (layer-major)
    uint16_t* Wpl  = Wph + 2 * 16384;                    // 2*16384

    int nb_n = (n + 255) / 256;
    int nb_e = (E + 255) / 256;

    // W pack (independent of CSR chain)
    packw_kernel<<<128, 256, 0, stream>>>(W1, W2, Wph, Wpl);

    // CSR build
    hipMemsetAsync(cnt, 0, (size_t)2 * n * sizeof(int), stream);   // cnt + curs
    count_kernel<<<nb_e, 256, 0, stream>>>(col, cnt, E);
    scanA_kernel<<<nbScan, 256, 0, stream>>>(cnt, bsum, n);
    scanB_kernel<<<1, 64, 0, stream>>>(bsum, bbase, offs, nbScan, n);
    scanC_kernel<<<nbScan, 256, 0, stream>>>(cnt, bbase, offs, dinv, n);
    fill_kernel<<<nb_e, 256, 0, stream>>>(row, col, offs, curs, adj, E);

    int nbG = (n + 63) / 64;

    // layer 1
    gemm_mfma_kernel<<<nbG, 256, 0, stream>>>(x, Wph, Wpl, dinv, xwb, n);
    agg_kernel<<<(n + 3) / 4, 256, 0, stream>>>((const uint32_t*)xwb, adj, offs, dinv, b1, h, n);
    // layer 2
    gemm_mfma_kernel<<<nbG, 256, 0, stream>>>(h, Wph + 16384, Wpl + 16384, dinv, xwb, n);
    agg_kernel<<<(n + 3) / 4, 256, 0, stream>>>((const uint32_t*)xwb, adj, offs, dinv, b2, h, n);

    // edge classifier (reuse xwb region for P1/P2)
    float* P1 = (float*)xwb;          // n*4
    float* P2 = P1 + (size_t)n * 4;   // n*4
    pq_kernel<<<nb_n, 256, 0, stream>>>(h, Wfc, bfc, P1, P2, n);
    edge2_kernel<<<nb_e, 256, 0, stream>>>(row, col, P1, P2, out, E);
}